// Round 7
// baseline (423.240 us; speedup 1.0000x reference)
//
#include <hip/hip_runtime.h>
#include <hip/hip_bf16.h>
#include <math.h>

constexpr int KN  = 100;            // K (multi_factor * top_k)
constexpr int DE  = 64;             // embedding dim
constexpr int CAT = 2 * KN * DE;    // 12800
constexpr int HID = 128;
constexpr int CHUNK = 4096;         // rows per pipeline chunk: xb chunk 105MB
                                    // + tables 49MB + w1t 3.3MB < 256MB L3

typedef __bf16          bf16x8   __attribute__((ext_vector_type(8)));
typedef float           f32x4    __attribute__((ext_vector_type(4)));
typedef unsigned short  ushort8v __attribute__((ext_vector_type(8)));
typedef unsigned short  ushort4v __attribute__((ext_vector_type(4)));

static __device__ __forceinline__ unsigned short f2bf(float f) {
    __hip_bfloat16 h = __float2bfloat16(f);
    return *reinterpret_cast<unsigned short*>(&h);
}

static __device__ __forceinline__ bf16x8 mk_frag(ushort4v lo, ushort4v hi) {
    union { ushort8v u; bf16x8 b; } c;
    c.u = (ushort8v){ lo[0], lo[1], lo[2], lo[3], hi[0], hi[1], hi[2], hi[3] };
    return c.b;
}

// ---------------------------------------------------------------------------
// prep: 4 fp32->bf16 table conversions in one launch (blockIdx.y = segment)
// ---------------------------------------------------------------------------
__global__ __launch_bounds__(256) void cvt4(
    const float* __restrict__ a0, unsigned short* __restrict__ o0, int n0,
    const float* __restrict__ a1, unsigned short* __restrict__ o1, int n1,
    const float* __restrict__ a2, unsigned short* __restrict__ o2, int n2,
    const float* __restrict__ a3, unsigned short* __restrict__ o3, int n3)
{
    const float* in; unsigned short* out; int n4;
    switch (blockIdx.y) {
        case 0:  in = a0; out = o0; n4 = n0; break;
        case 1:  in = a1; out = o1; n4 = n1; break;
        case 2:  in = a2; out = o2; n4 = n2; break;
        default: in = a3; out = o3; n4 = n3; break;
    }
    for (int i = blockIdx.x * 256 + threadIdx.x; i < n4; i += gridDim.x * 256) {
        float4 v = ((const float4*)in)[i];
        ushort4v o = { f2bf(v.x), f2bf(v.y), f2bf(v.z), f2bf(v.w) };
        ((ushort4v*)out)[i] = o;
    }
}

// ---------------------------------------------------------------------------
// prep: w1t[n][k] = bf16(W1[k][n]) (unchanged, known-good)
// ---------------------------------------------------------------------------
__global__ __launch_bounds__(256) void prep_w1t(
    const float* __restrict__ W1, unsigned short* __restrict__ w1t)
{
    __shared__ unsigned short T[HID][72];
    const int t  = threadIdx.x;
    const int k0 = blockIdx.x * 64;

    for (int idx = t; idx < 64 * HID; idx += 256) {
        int kk = idx >> 7, n = idx & 127;
        T[n][kk] = f2bf(W1[(size_t)(k0 + kk) * HID + n]);
    }
    __syncthreads();
    for (int idx = t; idx < HID * 16; idx += 256) {
        int n = idx >> 4, c4 = idx & 15;
        *(ushort4v*)&w1t[(size_t)n * CAT + k0 + c4 * 4] =
            *(const ushort4v*)&T[n][c4 * 4];
    }
}

// ---------------------------------------------------------------------------
// Kernel 1 (v6): same as v5b but REGULAR stores (we now WANT xb in L3; the
// chunked pipeline keeps the working set L3-resident so gathers hit L3).
// S fragments global->register (8 k-contiguous bf16/lane); row idx clamped.
// ---------------------------------------------------------------------------
__global__ __launch_bounds__(256) void einsum_mfma(
    const int* __restrict__ u_idx, const int* __restrict__ i_idx,
    const int* __restrict__ u_nbt, const int* __restrict__ i_nbt,
    const unsigned short* __restrict__ u_scr, const unsigned short* __restrict__ i_scr,
    const unsigned short* __restrict__ u_emb, const unsigned short* __restrict__ i_emb,
    unsigned short* __restrict__ xb, int b0)
{
    __shared__ __align__(16) unsigned short ET[64][136];  // 17.4 KB; reused as D-bounce
    __shared__ int nb[KN];

    const int t    = threadIdx.x;
    const int side = blockIdx.y;
    const int b    = b0 + blockIdx.x;

    const int*            idxs = side ? i_idx : u_idx;
    const int*            nbt  = side ? i_nbt : u_nbt;
    const unsigned short* scr  = side ? i_scr : u_scr;
    const unsigned short* emb  = side ? i_emb : u_emb;

    const ushort4v z4 = {0, 0, 0, 0};

    const int center = idxs[b];
    if (t < KN) nb[t] = nbt[(size_t)center * KN + t];

    // zero ET K-pad strip j in [100,128)
    for (int idx = t; idx < 64 * 7; idx += 256) {
        int r = idx / 7, c = idx - r * 7;
        *(ushort4v*)&ET[r][100 + c * 4] = z4;
    }
    __syncthreads();                           // nb ready

    // gather E with 4x4 u16 transpose: tile (j0,d4) -> ET[d4*4+c][j0*4..+3]
    for (int idx = t; idx < 25 * 16; idx += 256) {
        int d4 = idx / 25, j0 = idx - d4 * 25;
        ushort4v v0 = *(const ushort4v*)(emb + (size_t)nb[j0 * 4 + 0] * DE + d4 * 4);
        ushort4v v1 = *(const ushort4v*)(emb + (size_t)nb[j0 * 4 + 1] * DE + d4 * 4);
        ushort4v v2 = *(const ushort4v*)(emb + (size_t)nb[j0 * 4 + 2] * DE + d4 * 4);
        ushort4v v3 = *(const ushort4v*)(emb + (size_t)nb[j0 * 4 + 3] * DE + d4 * 4);
        ushort4v o0 = { v0[0], v1[0], v2[0], v3[0] };
        ushort4v o1 = { v0[1], v1[1], v2[1], v3[1] };
        ushort4v o2 = { v0[2], v1[2], v2[2], v3[2] };
        ushort4v o3 = { v0[3], v1[3], v2[3], v3[3] };
        *(ushort4v*)&ET[d4 * 4 + 0][j0 * 4] = o0;
        *(ushort4v*)&ET[d4 * 4 + 1][j0 * 4] = o1;
        *(ushort4v*)&ET[d4 * 4 + 2][j0 * 4] = o2;
        *(ushort4v*)&ET[d4 * 4 + 3][j0 * 4] = o3;
    }
    __syncthreads();

    const int w  = t >> 6;
    const int l  = t & 63;
    const int cl = l & 15;
    const int rg = l >> 4;

    // per-lane S row bases, clamped (k in [100,112) lanes gather row 99;
    // their acc rows are never stored)
    const unsigned short* srow[7];
    #pragma unroll
    for (int mt = 0; mt < 7; ++mt) {
        int kr = mt * 16 + cl;
        if (kr > KN - 1) kr = KN - 1;
        srow[mt] = scr + (size_t)nb[kr] * KN;
    }

    f32x4 acc[7];
    #pragma unroll
    for (int m = 0; m < 7; ++m) acc[m] = (f32x4){0.f, 0.f, 0.f, 0.f};

    #pragma unroll
    for (int ks = 0; ks < 4; ++ks) {
        const int k0 = ks * 32 + rg * 8;
        bf16x8 bfrag = *(const bf16x8*)&ET[w * 16 + cl][k0];
        #pragma unroll
        for (int mt = 0; mt < 7; ++mt) {
            ushort4v lo, hi;
            if (ks < 3) {                        // k0 in [0,88]: fully valid
                lo = *(const ushort4v*)(srow[mt] + k0);
                hi = *(const ushort4v*)(srow[mt] + k0 + 4);
            } else if (rg == 0) {                // k 96..99 valid, 100..103 zero
                lo = *(const ushort4v*)(srow[mt] + 96);
                hi = z4;
            } else {                             // k >= 104: all pad
                lo = z4; hi = z4;
            }
            bf16x8 afrag = mk_frag(lo, hi);
            acc[mt] = __builtin_amdgcn_mfma_f32_16x16x32_bf16(afrag, bfrag, acc[mt], 0, 0, 0);
        }
    }
    __syncthreads();                             // all ET reads done

    // bounce D through LDS (alias over ET; stride 72 ushorts)
    unsigned short* X = &ET[0][0];
    #pragma unroll
    for (int mt = 0; mt < 7; ++mt) {
        #pragma unroll
        for (int rr = 0; rr < 4; ++rr) {
            int k = mt * 16 + rg * 4 + rr;
            if (k < KN) X[k * 72 + w * 16 + cl] = f2bf(acc[mt][rr]);
        }
    }
    __syncthreads();

    // coalesced store (regular: we WANT L3 residency for the mlp's read)
    unsigned short* xr = xb + (size_t)blockIdx.x * CAT + side * (KN * DE);
    for (int idx = t; idx < KN * 8; idx += 256) {
        int r = idx >> 3, c8 = idx & 7;
        *(ushort8v*)&xr[r * DE + c8 * 8] = *(const ushort8v*)&X[r * 72 + c8 * 8];
    }
}

// ---------------------------------------------------------------------------
// Kernel 2 (v6): bf16 MFMA MLP, BM=16 rows/block so a 4096-row chunk still
// fills 256 blocks (1/CU).  Wave w owns cols w*32..+32; acc[2] (1 Mt x 2 Nt).
// ---------------------------------------------------------------------------
__global__ __launch_bounds__(256) void mlp_kernel(
    const unsigned short* __restrict__ xb, const unsigned short* __restrict__ w1t,
    const float* __restrict__ b1, const float* __restrict__ W2,
    const float* __restrict__ b2, float* __restrict__ out, int b0)
{
    __shared__ unsigned short A[16][136];     // 4.4 KB
    __shared__ unsigned short Bt[HID][136];   // 34.8 KB
    __shared__ float red[4][16];

    const int t    = threadIdx.x;
    const int w    = t >> 6;
    const int l    = t & 63;
    const int cl   = l & 15;
    const int rgrp = l >> 4;
    const int row0 = blockIdx.x * 16;

    f32x4 acc[2];
    acc[0] = (f32x4){0.f, 0.f, 0.f, 0.f};
    acc[1] = (f32x4){0.f, 0.f, 0.f, 0.f};

    for (int kb = 0; kb < CAT; kb += 128) {
        if (kb) __syncthreads();
        // stage A: 16 rows x 128 k = 256 16B-chunks, 1/thread
        {
            int r = t >> 4, c16 = t & 15;
            *(ushort8v*)&A[r][c16 * 8] =
                *(const ushort8v*)&xb[(size_t)(row0 + r) * CAT + kb + c16 * 8];
        }
        #pragma unroll
        for (int i = 0; i < 8; ++i) {
            int c = t + i * 256;
            int n = c >> 4, c16 = c & 15;
            *(ushort8v*)&Bt[n][c16 * 8] =
                *(const ushort8v*)&w1t[(size_t)n * CAT + kb + c16 * 8];
        }
        __syncthreads();

        #pragma unroll
        for (int ks = 0; ks < 4; ++ks) {
            const int kcol = ks * 32 + rgrp * 8;
            bf16x8 a0 = *(const bf16x8*)&A[cl][kcol];
            bf16x8 v0 = *(const bf16x8*)&Bt[w * 32 + cl][kcol];
            bf16x8 v1 = *(const bf16x8*)&Bt[w * 32 + 16 + cl][kcol];
            acc[0] = __builtin_amdgcn_mfma_f32_16x16x32_bf16(a0, v0, acc[0], 0, 0, 0);
            acc[1] = __builtin_amdgcn_mfma_f32_16x16x32_bf16(a0, v1, acc[1], 0, 0, 0);
        }
    }

    const float b1c0 = b1[w * 32 + cl];
    const float b1c1 = b1[w * 32 + 16 + cl];
    const float w2c0 = W2[w * 32 + cl];
    const float w2c1 = W2[w * 32 + 16 + cl];

    #pragma unroll
    for (int r = 0; r < 4; ++r) {
        float h0 = fmaxf(acc[0][r] + b1c0, 0.f);
        float h1 = fmaxf(acc[1][r] + b1c1, 0.f);
        float p  = fmaf(h0, w2c0, h1 * w2c1);
        p += __shfl_xor(p, 1, 64);
        p += __shfl_xor(p, 2, 64);
        p += __shfl_xor(p, 4, 64);
        p += __shfl_xor(p, 8, 64);
        if (cl == 0) red[w][rgrp * 4 + r] = p;
    }
    __syncthreads();
    if (t < 16) {
        float o = red[0][t] + red[1][t] + red[2][t] + red[3][t] + b2[0];
        o = fmaxf(o, 0.f);
        out[b0 + row0 + t] = 1.f / (1.f + expf(-o));
    }
}

// ---------------------------------------------------------------------------
extern "C" void kernel_launch(void* const* d_in, const int* in_sizes, int n_in,
                              void* d_out, int out_size, void* d_ws, size_t ws_size,
                              hipStream_t stream)
{
    const int*   user_idxs = (const int*)d_in[0];
    const int*   item_idxs = (const int*)d_in[1];
    const int*   user_nbt  = (const int*)d_in[2];
    const int*   item_nbt  = (const int*)d_in[3];
    const float* user_scr  = (const float*)d_in[4];
    const float* item_scr  = (const float*)d_in[5];
    const float* user_emb  = (const float*)d_in[6];
    const float* item_emb  = (const float*)d_in[7];
    const float* W1        = (const float*)d_in[8];
    const float* b1        = (const float*)d_in[9];
    const float* W2        = (const float*)d_in[10];
    const float* b2        = (const float*)d_in[11];
    float*       out       = (float*)d_out;

    const int B = in_sizes[0];      // 8192

    // ws layout: [w1t][us_bf][is_bf][ue_bf][ie_bf][xb]
    char* p = (char*)d_ws;
    unsigned short* w1t   = (unsigned short*)p;  p += (size_t)HID * CAT * 2;
    unsigned short* us_bf = (unsigned short*)p;  p += (size_t)in_sizes[4] * 2;
    unsigned short* is_bf = (unsigned short*)p;  p += (size_t)in_sizes[5] * 2;
    unsigned short* ue_bf = (unsigned short*)p;  p += (size_t)in_sizes[6] * 2;
    unsigned short* ie_bf = (unsigned short*)p;  p += (size_t)in_sizes[7] * 2;
    unsigned short* xb    = (unsigned short*)p;
    const size_t fixed = (size_t)(p - (char*)d_ws);

    const size_t row_bytes = (size_t)CAT * sizeof(unsigned short);
    long max_rows = (long)((ws_size - fixed) / row_bytes);
    int chunk = (int)((max_rows / 32) * 32);
    if (chunk > CHUNK) chunk = CHUNK;       // L3-residency cap
    if (chunk > B) chunk = B;
    if (chunk < 32) chunk = 32;

    prep_w1t<<<CAT / 64, 256, 0, stream>>>(W1, w1t);
    cvt4<<<dim3(512, 4), 256, 0, stream>>>(
        user_scr, us_bf, in_sizes[4] / 4,
        item_scr, is_bf, in_sizes[5] / 4,
        user_emb, ue_bf, in_sizes[6] / 4,
        item_emb, ie_bf, in_sizes[7] / 4);

    for (int b0 = 0; b0 < B; b0 += chunk) {
        int rows = (B - b0 < chunk) ? (B - b0) : chunk;
        einsum_mfma<<<dim3(rows, 2), 256, 0, stream>>>(
            user_idxs, item_idxs, user_nbt, item_nbt,
            us_bf, is_bf, ue_bf, ie_bf, xb, b0);
        mlp_kernel<<<(rows + 15) / 16, 256, 0, stream>>>(
            xb, w1t, b1, W2, b2, out, b0);
    }
}

// Round 8
// 422.820 us; speedup vs baseline: 1.0010x; 1.0010x over previous
//
#include <hip/hip_runtime.h>
#include <hip/hip_bf16.h>
#include <math.h>

constexpr int KN  = 100;            // K (multi_factor * top_k)
constexpr int DE  = 64;             // embedding dim
constexpr int CAT = 2 * KN * DE;    // 12800
constexpr int HID = 128;
constexpr int CHUNK = 4096;         // rows per pipeline chunk: xb chunk 105MB
                                    // + tables 49MB + w1t 3.3MB < 256MB L3

typedef __bf16          bf16x8   __attribute__((ext_vector_type(8)));
typedef float           f32x4    __attribute__((ext_vector_type(4)));
typedef unsigned short  ushort8v __attribute__((ext_vector_type(8)));
typedef unsigned short  ushort4v __attribute__((ext_vector_type(4)));

static __device__ __forceinline__ unsigned short f2bf(float f) {
    __hip_bfloat16 h = __float2bfloat16(f);
    return *reinterpret_cast<unsigned short*>(&h);
}

static __device__ __forceinline__ bf16x8 mk_frag(ushort4v lo, ushort4v hi) {
    union { ushort8v u; bf16x8 b; } c;
    c.u = (ushort8v){ lo[0], lo[1], lo[2], lo[3], hi[0], hi[1], hi[2], hi[3] };
    return c.b;
}

// ---------------------------------------------------------------------------
// prep: 4 fp32->bf16 table conversions in one launch (blockIdx.y = segment)
// ---------------------------------------------------------------------------
__global__ __launch_bounds__(256) void cvt4(
    const float* __restrict__ a0, unsigned short* __restrict__ o0, int n0,
    const float* __restrict__ a1, unsigned short* __restrict__ o1, int n1,
    const float* __restrict__ a2, unsigned short* __restrict__ o2, int n2,
    const float* __restrict__ a3, unsigned short* __restrict__ o3, int n3)
{
    const float* in; unsigned short* out; int n4;
    switch (blockIdx.y) {
        case 0:  in = a0; out = o0; n4 = n0; break;
        case 1:  in = a1; out = o1; n4 = n1; break;
        case 2:  in = a2; out = o2; n4 = n2; break;
        default: in = a3; out = o3; n4 = n3; break;
    }
    for (int i = blockIdx.x * 256 + threadIdx.x; i < n4; i += gridDim.x * 256) {
        float4 v = ((const float4*)in)[i];
        ushort4v o = { f2bf(v.x), f2bf(v.y), f2bf(v.z), f2bf(v.w) };
        ((ushort4v*)out)[i] = o;
    }
}

// ---------------------------------------------------------------------------
// prep: w1t[n][k] = bf16(W1[k][n]) (unchanged, known-good)
// ---------------------------------------------------------------------------
__global__ __launch_bounds__(256) void prep_w1t(
    const float* __restrict__ W1, unsigned short* __restrict__ w1t)
{
    __shared__ unsigned short T[HID][72];
    const int t  = threadIdx.x;
    const int k0 = blockIdx.x * 64;

    for (int idx = t; idx < 64 * HID; idx += 256) {
        int kk = idx >> 7, n = idx & 127;
        T[n][kk] = f2bf(W1[(size_t)(k0 + kk) * HID + n]);
    }
    __syncthreads();
    for (int idx = t; idx < HID * 16; idx += 256) {
        int n = idx >> 4, c4 = idx & 15;
        *(ushort4v*)&w1t[(size_t)n * CAT + k0 + c4 * 4] =
            *(const ushort4v*)&T[n][c4 * 4];
    }
}

// ---------------------------------------------------------------------------
// Kernel 1 (unchanged from round 7 — proven 62us/chunk with L3-resident
// tables): S fragments global->register, E LDS-staged, regular xb stores.
// ---------------------------------------------------------------------------
__global__ __launch_bounds__(256) void einsum_mfma(
    const int* __restrict__ u_idx, const int* __restrict__ i_idx,
    const int* __restrict__ u_nbt, const int* __restrict__ i_nbt,
    const unsigned short* __restrict__ u_scr, const unsigned short* __restrict__ i_scr,
    const unsigned short* __restrict__ u_emb, const unsigned short* __restrict__ i_emb,
    unsigned short* __restrict__ xb, int b0)
{
    __shared__ __align__(16) unsigned short ET[64][136];  // 17.4 KB; reused as D-bounce
    __shared__ int nb[KN];

    const int t    = threadIdx.x;
    const int side = blockIdx.y;
    const int b    = b0 + blockIdx.x;

    const int*            idxs = side ? i_idx : u_idx;
    const int*            nbt  = side ? i_nbt : u_nbt;
    const unsigned short* scr  = side ? i_scr : u_scr;
    const unsigned short* emb  = side ? i_emb : u_emb;

    const ushort4v z4 = {0, 0, 0, 0};

    const int center = idxs[b];
    if (t < KN) nb[t] = nbt[(size_t)center * KN + t];

    for (int idx = t; idx < 64 * 7; idx += 256) {
        int r = idx / 7, c = idx - r * 7;
        *(ushort4v*)&ET[r][100 + c * 4] = z4;
    }
    __syncthreads();                           // nb ready

    for (int idx = t; idx < 25 * 16; idx += 256) {
        int d4 = idx / 25, j0 = idx - d4 * 25;
        ushort4v v0 = *(const ushort4v*)(emb + (size_t)nb[j0 * 4 + 0] * DE + d4 * 4);
        ushort4v v1 = *(const ushort4v*)(emb + (size_t)nb[j0 * 4 + 1] * DE + d4 * 4);
        ushort4v v2 = *(const ushort4v*)(emb + (size_t)nb[j0 * 4 + 2] * DE + d4 * 4);
        ushort4v v3 = *(const ushort4v*)(emb + (size_t)nb[j0 * 4 + 3] * DE + d4 * 4);
        ushort4v o0 = { v0[0], v1[0], v2[0], v3[0] };
        ushort4v o1 = { v0[1], v1[1], v2[1], v3[1] };
        ushort4v o2 = { v0[2], v1[2], v2[2], v3[2] };
        ushort4v o3 = { v0[3], v1[3], v2[3], v3[3] };
        *(ushort4v*)&ET[d4 * 4 + 0][j0 * 4] = o0;
        *(ushort4v*)&ET[d4 * 4 + 1][j0 * 4] = o1;
        *(ushort4v*)&ET[d4 * 4 + 2][j0 * 4] = o2;
        *(ushort4v*)&ET[d4 * 4 + 3][j0 * 4] = o3;
    }
    __syncthreads();

    const int w  = t >> 6;
    const int l  = t & 63;
    const int cl = l & 15;
    const int rg = l >> 4;

    const unsigned short* srow[7];
    #pragma unroll
    for (int mt = 0; mt < 7; ++mt) {
        int kr = mt * 16 + cl;
        if (kr > KN - 1) kr = KN - 1;
        srow[mt] = scr + (size_t)nb[kr] * KN;
    }

    f32x4 acc[7];
    #pragma unroll
    for (int m = 0; m < 7; ++m) acc[m] = (f32x4){0.f, 0.f, 0.f, 0.f};

    #pragma unroll
    for (int ks = 0; ks < 4; ++ks) {
        const int k0 = ks * 32 + rg * 8;
        bf16x8 bfrag = *(const bf16x8*)&ET[w * 16 + cl][k0];
        #pragma unroll
        for (int mt = 0; mt < 7; ++mt) {
            ushort4v lo, hi;
            if (ks < 3) {
                lo = *(const ushort4v*)(srow[mt] + k0);
                hi = *(const ushort4v*)(srow[mt] + k0 + 4);
            } else if (rg == 0) {
                lo = *(const ushort4v*)(srow[mt] + 96);
                hi = z4;
            } else {
                lo = z4; hi = z4;
            }
            bf16x8 afrag = mk_frag(lo, hi);
            acc[mt] = __builtin_amdgcn_mfma_f32_16x16x32_bf16(afrag, bfrag, acc[mt], 0, 0, 0);
        }
    }
    __syncthreads();

    unsigned short* X = &ET[0][0];
    #pragma unroll
    for (int mt = 0; mt < 7; ++mt) {
        #pragma unroll
        for (int rr = 0; rr < 4; ++rr) {
            int k = mt * 16 + rg * 4 + rr;
            if (k < KN) X[k * 72 + w * 16 + cl] = f2bf(acc[mt][rr]);
        }
    }
    __syncthreads();

    unsigned short* xr = xb + (size_t)blockIdx.x * CAT + side * (KN * DE);
    for (int idx = t; idx < KN * 8; idx += 256) {
        int r = idx >> 3, c8 = idx & 7;
        *(ushort8v*)&xr[r * DE + c8 * 8] = *(const ushort8v*)&X[r * 72 + c8 * 8];
    }
}

// ---------------------------------------------------------------------------
// Kernel 2 (v8): bf16 MFMA MLP, restructured for latency hiding.
// 1024 threads = 16 waves (4/SIMD).  BM=32 rows; wave w -> row-tile (w>>3),
// col-group (w&7)*16.  Double-buffered LDS: stage K-step s+1 while MFMA on
// step s, one barrier per step.  Fused bias/relu/W2/sigmoid epilogue.
// ---------------------------------------------------------------------------
__global__ __launch_bounds__(1024) void mlp_kernel(
    const unsigned short* __restrict__ xb, const unsigned short* __restrict__ w1t,
    const float* __restrict__ b1, const float* __restrict__ W2,
    const float* __restrict__ b2, float* __restrict__ out, int b0)
{
    __shared__ unsigned short A[2][32][136];    // 17.4 KB
    __shared__ unsigned short Bt[2][HID][136];  // 69.6 KB
    __shared__ float red[16][16];               // 1 KB

    const int t   = threadIdx.x;
    const int w   = t >> 6;
    const int l   = t & 63;
    const int cl  = l & 15;
    const int rg  = l >> 4;
    const int mt  = w >> 3;         // row-tile (0/1)
    const int ng  = w & 7;          // col-group (16 cols each)
    const int row0 = blockIdx.x * 32;

    auto stage = [&](int buf, int kb) {
        if (t < 512) {              // A: 32 rows x 16 b128-chunks
            int r = t >> 4, c16 = t & 15;
            *(ushort8v*)&A[buf][r][c16 * 8] =
                *(const ushort8v*)&xb[(size_t)(row0 + r) * CAT + kb + c16 * 8];
        }
        #pragma unroll
        for (int i = 0; i < 2; ++i) {   // Bt: 128 rows x 16 chunks
            int c = t + i * 1024;
            int n = c >> 4, c16 = c & 15;
            *(ushort8v*)&Bt[buf][n][c16 * 8] =
                *(const ushort8v*)&w1t[(size_t)n * CAT + kb + c16 * 8];
        }
    };

    f32x4 acc = (f32x4){0.f, 0.f, 0.f, 0.f};

    stage(0, 0);
    __syncthreads();

    constexpr int NSTEP = CAT / 128;    // 100
    for (int s = 0; s < NSTEP; ++s) {
        const int cur = s & 1;
        if (s + 1 < NSTEP) stage(cur ^ 1, (s + 1) * 128);
        #pragma unroll
        for (int ks = 0; ks < 4; ++ks) {
            const int kcol = ks * 32 + rg * 8;
            bf16x8 a = *(const bf16x8*)&A[cur][mt * 16 + cl][kcol];
            bf16x8 bv = *(const bf16x8*)&Bt[cur][ng * 16 + cl][kcol];
            acc = __builtin_amdgcn_mfma_f32_16x16x32_bf16(a, bv, acc, 0, 0, 0);
        }
        __syncthreads();
    }

    // epilogue: h = relu(acc + b1[col]); partial p = h*W2[col]; reduce over
    // the 16 col-lanes; cross-wave (8 col-groups) via LDS.
    const int col = ng * 16 + cl;
    const float b1c = b1[col];
    const float w2c = W2[col];

    #pragma unroll
    for (int r = 0; r < 4; ++r) {
        float h = fmaxf(acc[r] + b1c, 0.f);
        float p = h * w2c;
        p += __shfl_xor(p, 1, 64);
        p += __shfl_xor(p, 2, 64);
        p += __shfl_xor(p, 4, 64);
        p += __shfl_xor(p, 8, 64);
        if (cl == 0) red[w][rg * 4 + r] = p;
    }
    __syncthreads();
    if (t < 32) {
        float o = b2[0];
        #pragma unroll
        for (int g = 0; g < 8; ++g) o += red[(t >> 4) * 8 + g][t & 15];
        o = fmaxf(o, 0.f);
        out[b0 + row0 + t] = 1.f / (1.f + expf(-o));
    }
}

// ---------------------------------------------------------------------------
extern "C" void kernel_launch(void* const* d_in, const int* in_sizes, int n_in,
                              void* d_out, int out_size, void* d_ws, size_t ws_size,
                              hipStream_t stream)
{
    const int*   user_idxs = (const int*)d_in[0];
    const int*   item_idxs = (const int*)d_in[1];
    const int*   user_nbt  = (const int*)d_in[2];
    const int*   item_nbt  = (const int*)d_in[3];
    const float* user_scr  = (const float*)d_in[4];
    const float* item_scr  = (const float*)d_in[5];
    const float* user_emb  = (const float*)d_in[6];
    const float* item_emb  = (const float*)d_in[7];
    const float* W1        = (const float*)d_in[8];
    const float* b1        = (const float*)d_in[9];
    const float* W2        = (const float*)d_in[10];
    const float* b2        = (const float*)d_in[11];
    float*       out       = (float*)d_out;

    const int B = in_sizes[0];      // 8192

    // ws layout: [w1t][us_bf][is_bf][ue_bf][ie_bf][xb]
    char* p = (char*)d_ws;
    unsigned short* w1t   = (unsigned short*)p;  p += (size_t)HID * CAT * 2;
    unsigned short* us_bf = (unsigned short*)p;  p += (size_t)in_sizes[4] * 2;
    unsigned short* is_bf = (unsigned short*)p;  p += (size_t)in_sizes[5] * 2;
    unsigned short* ue_bf = (unsigned short*)p;  p += (size_t)in_sizes[6] * 2;
    unsigned short* ie_bf = (unsigned short*)p;  p += (size_t)in_sizes[7] * 2;
    unsigned short* xb    = (unsigned short*)p;
    const size_t fixed = (size_t)(p - (char*)d_ws);

    const size_t row_bytes = (size_t)CAT * sizeof(unsigned short);
    long max_rows = (long)((ws_size - fixed) / row_bytes);
    int chunk = (int)((max_rows / 32) * 32);
    if (chunk > CHUNK) chunk = CHUNK;       // L3-residency cap
    if (chunk > B) chunk = B;
    if (chunk < 32) chunk = 32;

    prep_w1t<<<CAT / 64, 256, 0, stream>>>(W1, w1t);
    cvt4<<<dim3(512, 4), 256, 0, stream>>>(
        user_scr, us_bf, in_sizes[4] / 4,
        item_scr, is_bf, in_sizes[5] / 4,
        user_emb, ue_bf, in_sizes[6] / 4,
        item_emb, ie_bf, in_sizes[7] / 4);

    for (int b0 = 0; b0 < B; b0 += chunk) {
        int rows = (B - b0 < chunk) ? (B - b0) : chunk;
        einsum_mfma<<<dim3(rows, 2), 256, 0, stream>>>(
            user_idxs, item_idxs, user_nbt, item_nbt,
            us_bf, is_bf, ue_bf, ie_bf, xb, b0);
        mlp_kernel<<<rows / 32, 1024, 0, stream>>>(
            xb, w1t, b1, W2, b2, out, b0);
    }
}